// Round 11
// baseline (130.968 us; speedup 1.0000x reference)
//
#include <hip/hip_runtime.h>
#include <math.h>

#define NQ 12
#define NL 6
#define BATCHN 8192
#define DIN 512

typedef _Float16 f16;
typedef __attribute__((ext_vector_type(8)))  _Float16 f16x8;
typedef __attribute__((ext_vector_type(16))) float    f32x16;
typedef unsigned int u32;
typedef __attribute__((ext_vector_type(4))) u32 u32x4;
typedef __attribute__((ext_vector_type(2))) int i32x2;

// ============================================================================
// 10-matmul formulation (R10). State = 64x64 (P: wires 0-5, Q: wires 6-11).
// MFMA contracts the reg-resident factor and swaps residency; CNOT chain
// sigma(d)=d^(d<<1) = sigmaP (x) sigmaQ (x) condflip(wire5->wire6); sigmaP/Q
// folded into next matrices (F6 = prefix-xor), cond-flip folded into the next
// repack (1 dpp + 1 bfi per word) or the measurement sign algebra.
// R10: LAYER 0 acts on a PRODUCT state -> Kron(RY_layer0) is a per-qubit
// 2-vector rotation (24 fma), and its cond-flip on a product state is just a
// wire-6-swapped q-product for odd-parity k slots -> MM0+MM1 eliminated,
// state built directly as MM2's A-fragments. 12 -> 10 matmul steps.
//   MFMA 32x32x16 f16 layouts:
//   A[m][k]: m=lane&31, k=8*(lane>>5)+i ; B[k][n]: n=lane&31, k=8*(lane>>5)+i
//   D[m][n]: n=lane&31, m=(reg&3)+8*(reg>>2)+4*(lane>>5), tiles d[mt][nt].
// R5: accumulate directly into d (no temp) or scratch-spill.
// R8/R9: permlane32_swap repack; fold parity class indexes the OLD m-tile (s).
// ============================================================================

__device__ __forceinline__ u32 pkrtz(float a, float b) {
  auto p = __builtin_amdgcn_cvt_pkrtz(a, b);   // __fp16 ext_vector(2)
  return __builtin_bit_cast(u32, p);
}
__device__ __forceinline__ u32 bperm(int addr, u32 v) {
  return (u32)__builtin_amdgcn_ds_bpermute(addr, (int)v);
}
__device__ __forceinline__ float dppx1(float v) {  // lane xor 1 (quad_perm)
  return __int_as_float(__builtin_amdgcn_mov_dpp(__float_as_int(v), 0xB1, 0xF, 0xF, true));
}
__device__ __forceinline__ u32 dppx1u(u32 v) {
  return (u32)__builtin_amdgcn_mov_dpp((int)v, 0xB1, 0xF, 0xF, true);
}
__device__ __forceinline__ float dppx2(float v) {
  return __int_as_float(__builtin_amdgcn_mov_dpp(__float_as_int(v), 0x4E, 0xF, 0xF, true));
}
__device__ __forceinline__ float dppx8(float v) {  // row_ror:8 == xor 8
  return __int_as_float(__builtin_amdgcn_mov_dpp(__float_as_int(v), 0x128, 0xF, 0xF, true));
}
template <int PAT>
__device__ __forceinline__ float swzf(float v) {
  return __int_as_float(__builtin_amdgcn_ds_swizzle(__float_as_int(v), PAT));
}
__device__ __forceinline__ float wave_sum(float v) {
  v += dppx1(v);
  v += dppx2(v);
  v += swzf<0x101F>(v);   // xor 4
  v += dppx8(v);
  v += swzf<0x401F>(v);   // xor 16
  v += __shfl_xor(v, 32, 64);
  return v;
}
__device__ __forceinline__ f16x8 asf(const u32 a[4]) {
  u32x4 v; v.x = a[0]; v.y = a[1]; v.z = a[2]; v.w = a[3];
  return __builtin_bit_cast(f16x8, v);
}
__device__ __forceinline__ f16x8 ldB(const u32* __restrict__ p, int off) {
  u32x4 v = *(const u32x4*)(p + off);
  return __builtin_bit_cast(f16x8, v);
}

// half-swap across the lane-32 boundary: returns the two A-frag words.
#if __has_builtin(__builtin_amdgcn_permlane32_swap)
__device__ __forceinline__ void pswap(u32& a, u32& b) {
  i32x2 r = __builtin_amdgcn_permlane32_swap((int)a, (int)b, false, false);
  a = (u32)r.x; b = (u32)r.y;
}
#else
#define PSWAP_FALLBACK 1
__device__ __forceinline__ void pswap_fb(u32& a, u32& b, bool hi, int axor) {
  u32 xa = bperm(axor, a), xb = bperm(axor, b);
  u32 na = hi ? xb : a;
  u32 nb = hi ? b : xa;
  a = na; b = nb;
}
#endif

// conditional lane-xor-1 on a packed word (bfi idiom; halves have opposite
// flip conditions).
__device__ __forceinline__ u32 foldw(u32 w, u32 m) {
  u32 partner = dppx1u(w);
  return (m & partner) | (~m & w);
}

// ---------- setup: matrices (fp16, B-fragment order) from weights -----------
// mm=0,1 are unused since R10 (layer 0 folded into the init) but writing them
// is harmless and keeps indexing simple.
__global__ void setup_mats(const float* __restrict__ weights, u32* __restrict__ Bbuf) {
  const int mm = blockIdx.x >> 3;   // 0..11 ; layer = mm>>1, side: 0=P,1=Q
  const int l  = mm >> 1;
  const int qs = mm & 1;
  __shared__ float c6[6], s6[6];
  if (threadIdx.x < 6) {
    float h = 0.5f * weights[l * NQ + qs * 6 + threadIdx.x];
    c6[threadIdx.x] = cosf(h);
    s6[threadIdx.x] = sinf(h);
  }
  __syncthreads();
  const int t = (blockIdx.x & 7) * 256 + threadIdx.x;   // 0..2047
  const int lane = (t >> 2) & 63;
  const int fk   = t >> 8;          // nt*4 + kt
  const int kt   = fk & 3;
  const int nt   = fk >> 2;
  const int n     = nt * 32 + (lane & 31);
  const int kbase = kt * 16 + (lane >> 5) * 8 + (t & 3) * 2;
  float v[2];
  #pragma unroll
  for (int u = 0; u < 2; ++u) {
    int k = kbase + u;
    int bb = k;
    if (l >= 1) { bb ^= bb << 1; bb ^= bb << 2; bb ^= bb << 4; bb &= 63; } // F6 = prefix-xor
    float prod = 1.f;
    #pragma unroll
    for (int w = 0; w < 6; ++w) {
      const int aw = (n >> w) & 1, bw = (bb >> w) & 1;
      prod *= (aw == bw) ? c6[w] : (aw ? s6[w] : -s6[w]);  // RY: [[c,-s],[s,c]]
    }
    v[u] = prod;
  }
  Bbuf[mm * 2048 + t] = pkrtz(v[0], v[1]);
}

// ---------- one matmul step: repack prev D -> A frags, 16 MFMA --------------
template <bool FOLD>
__device__ __forceinline__ void mm_step(f32x16 (&d)[2][2], const u32* __restrict__ Bl,
                                        bool hi, int axor, u32 maskA, u32 maskB) {
  u32 fr[2][4][4];
  #pragma unroll
  for (int kt = 0; kt < 4; ++kt) {
    const int s  = kt >> 1;
    const int b0 = 4 * ((2 * kt) & 3);
    const int b1 = 4 * ((2 * kt + 1) & 3);
    #pragma unroll
    for (int mt = 0; mt < 2; ++mt) {
      u32 p0a = pkrtz(d[s][mt][b0 + 0], d[s][mt][b0 + 1]);
      u32 p0b = pkrtz(d[s][mt][b0 + 2], d[s][mt][b0 + 3]);
      u32 p1a = pkrtz(d[s][mt][b1 + 0], d[s][mt][b1 + 1]);
      u32 p1b = pkrtz(d[s][mt][b1 + 2], d[s][mt][b1 + 3]);
      if (FOLD) {
        const int PAR4[4] = {0, 1, 1, 0};
        const int ka = (PAR4[b0 >> 2] + s) & 1;   // low-half class of p0a
        const int kc = (PAR4[b1 >> 2] + s) & 1;   // low-half class of p1a
        p0a = foldw(p0a, ka ? maskB : maskA);
        p0b = foldw(p0b, ka ? maskA : maskB);
        p1a = foldw(p1a, kc ? maskB : maskA);
        p1b = foldw(p1b, kc ? maskA : maskB);
      }
#ifdef PSWAP_FALLBACK
      pswap_fb(p0a, p1a, hi, axor);
      pswap_fb(p0b, p1b, hi, axor);
#else
      pswap(p0a, p1a);
      pswap(p0b, p1b);
#endif
      fr[mt][kt][0] = p0a;
      fr[mt][kt][1] = p0b;
      fr[mt][kt][2] = p1a;
      fr[mt][kt][3] = p1b;
    }
  }
  #pragma unroll
  for (int kt = 0; kt < 4; ++kt) {
    f16x8 A0 = asf(fr[0][kt]);
    f16x8 A1 = asf(fr[1][kt]);
    f16x8 B0 = ldB(Bl, (0 * 4 + kt) * 256);
    f16x8 B1 = ldB(Bl, (1 * 4 + kt) * 256);
    if (kt == 0) {
      f32x16 z{};
      d[0][0] = __builtin_amdgcn_mfma_f32_32x32x16_f16(A0, B0, z, 0, 0, 0);
      d[0][1] = __builtin_amdgcn_mfma_f32_32x32x16_f16(A0, B1, z, 0, 0, 0);
      d[1][0] = __builtin_amdgcn_mfma_f32_32x32x16_f16(A1, B0, z, 0, 0, 0);
      d[1][1] = __builtin_amdgcn_mfma_f32_32x32x16_f16(A1, B1, z, 0, 0, 0);
    } else {
      d[0][0] = __builtin_amdgcn_mfma_f32_32x32x16_f16(A0, B0, d[0][0], 0, 0, 0);
      d[0][1] = __builtin_amdgcn_mfma_f32_32x32x16_f16(A0, B1, d[0][1], 0, 0, 0);
      d[1][0] = __builtin_amdgcn_mfma_f32_32x32x16_f16(A1, B0, d[1][0], 0, 0, 0);
      d[1][1] = __builtin_amdgcn_mfma_f32_32x32x16_f16(A1, B1, d[1][1], 0, 0, 0);
    }
  }
}

__global__ void __launch_bounds__(256) __attribute__((amdgpu_waves_per_eu(4)))
dqc_main(const float* __restrict__ x,
         const float* __restrict__ pre_w,
         const float* __restrict__ pre_b,
         const float* __restrict__ weights,
         const float* __restrict__ post_w,
         const float* __restrict__ post_b,
         const u32* __restrict__ Bbuf,
         float* __restrict__ out)
{
  const int lane = threadIdx.x & 63;
  const bool hi  = lane >= 32;
  const int b    = blockIdx.x * 4 + (threadIdx.x >> 6);
  const int axor = (lane ^ 32) << 2;
  // flip-partner masks: class k flips lower f16 when k ^ hi == 1.
  const u32 maskA = hi ? 0x0000FFFFu : 0xFFFF0000u;   // parity-class 0
  const u32 maskB = ~maskA;                            // parity-class 1

  // ---- pre-GEMM: pre[w] = x[b,:] . pre_w[w,:]
  float acc[NQ];
  const float* xr = x + (size_t)b * DIN + lane * 8;
  const float4 xa = *(const float4*)(xr);
  const float4 xb = *(const float4*)(xr + 4);
  #pragma unroll
  for (int w = 0; w < NQ; ++w) {
    const float* wr = pre_w + w * DIN + lane * 8;
    const float4 wa = *(const float4*)(wr);
    const float4 wb = *(const float4*)(wr + 4);
    acc[w] = xa.x * wa.x + xa.y * wa.y + xa.z * wa.z + xa.w * wa.w
           + xb.x * wb.x + xb.y * wb.y + xb.z * wb.z + xb.w * wb.w;
  }
  #pragma unroll
  for (int w = 0; w < NQ; ++w) acc[w] = wave_sum(acc[w]);

  const float PI_4 = 0.78539816339744830962f;
  const float INV_SQRT2 = 0.70710678118654752440f;
  float v0[NQ], v1[NQ];
  #pragma unroll
  for (int w = 0; w < NQ; ++w) {
    float h = (acc[w] + pre_b[w]) * PI_4;
    float s, c;
    sincosf(h, &s, &c);
    v0[w] = (c - s) * INV_SQRT2;
    v1[w] = (c + s) * INV_SQRT2;
  }

  // ---- R10: fold layer-0 RYs into the product state (exact, fp32):
  // u_w = RY(0.5*weights[0][w]) . v_w   (saves matmul steps 0 and 1)
  float u0[NQ], u1[NQ];
  #pragma unroll
  for (int w = 0; w < NQ; ++w) {
    float s, c;
    sincosf(0.5f * weights[w], &s, &c);
    u0[w] = c * v0[w] - s * v1[w];
    u1[w] = s * v0[w] + c * v1[w];
  }

  // ---- build MM2's A-frags directly, with layer-0's cond-flip applied:
  // element(m=q, k=p) = P(p) * Q(q ^ (par(p) & 1 on wire6)).
  // p = 16*kt + 8*hi + j: par(p) = PKT[kt] ^ hi ^ parity(j).
  float base8[8];   // wires 0-2 (j bits)
  #pragma unroll
  for (int j = 0; j < 8; ++j)
    base8[j] = ((j & 1) ? u1[0] : u0[0]) * ((j & 2) ? u1[1] : u0[1]) * ((j & 4) ? u1[2] : u0[2]);
  float hiP[4];     // wires 3(hi),4,5(kt bits)
  #pragma unroll
  for (int kt = 0; kt < 4; ++kt)
    hiP[kt] = (hi ? u1[3] : u0[3]) * ((kt & 1) ? u1[4] : u0[4]) * ((kt & 2) ? u1[5] : u0[5]);
  const float q5 = ((lane & 2) ? u1[7] : u0[7]) * ((lane & 4) ? u1[8] : u0[8])
                 * ((lane & 8) ? u1[9] : u0[9]) * ((lane & 16) ? u1[10] : u0[10]);
  const float qA = q5 * ((lane & 1) ? u1[6] : u0[6]);   // Q(q)
  const float qB = q5 * ((lane & 1) ? u0[6] : u1[6]);   // Q(q ^ wire6)
  const float qeven = hi ? qB : qA;   // class par(p)=0 (hi folded in)
  const float qodd  = hi ? qA : qB;   // class par(p)=1
  const float qe0 = qeven * u0[11], qo0 = qodd * u0[11];   // mt = 0 (wire11=0)
  const float qe1 = qeven * u1[11], qo1 = qodd * u1[11];   // mt = 1

  f32x16 d[2][2];
  {
    const u32* Bl = Bbuf + 2 * 2048 + lane * 4;   // matmul index 2 (layer-1 P, F6)
    const int PKT[4] = {0, 1, 1, 0};   // parity(kt)
    const int PDW[4] = {0, 1, 1, 0};   // parity(j=2*dw)
    #pragma unroll
    for (int kt = 0; kt < 4; ++kt) {
      u32 a0[4], a1[4];
      #pragma unroll
      for (int dw = 0; dw < 4; ++dw) {
        const float e0 = base8[2 * dw] * hiP[kt];
        const float e1 = base8[2 * dw + 1] * hiP[kt];
        const bool cls = (PKT[kt] ^ PDW[dw]) != 0;   // class of e0 (e1 is ^1)
        a0[dw] = pkrtz((cls ? qo0 : qe0) * e0, (cls ? qe0 : qo0) * e1);
        a1[dw] = pkrtz((cls ? qo1 : qe1) * e0, (cls ? qe1 : qo1) * e1);
      }
      f16x8 A0 = asf(a0), A1 = asf(a1);
      f16x8 B0 = ldB(Bl, (0 * 4 + kt) * 256);
      f16x8 B1 = ldB(Bl, (1 * 4 + kt) * 256);
      if (kt == 0) {
        f32x16 z{};
        d[0][0] = __builtin_amdgcn_mfma_f32_32x32x16_f16(A0, B0, z, 0, 0, 0);
        d[0][1] = __builtin_amdgcn_mfma_f32_32x32x16_f16(A0, B1, z, 0, 0, 0);
        d[1][0] = __builtin_amdgcn_mfma_f32_32x32x16_f16(A1, B0, z, 0, 0, 0);
        d[1][1] = __builtin_amdgcn_mfma_f32_32x32x16_f16(A1, B1, z, 0, 0, 0);
      } else {
        d[0][0] = __builtin_amdgcn_mfma_f32_32x32x16_f16(A0, B0, d[0][0], 0, 0, 0);
        d[0][1] = __builtin_amdgcn_mfma_f32_32x32x16_f16(A0, B1, d[0][1], 0, 0, 0);
        d[1][0] = __builtin_amdgcn_mfma_f32_32x32x16_f16(A1, B0, d[1][0], 0, 0, 0);
        d[1][1] = __builtin_amdgcn_mfma_f32_32x32x16_f16(A1, B1, d[1][1], 0, 0, 0);
      }
    }
  }

  // ---- MM 3..11. Flip after odd (Q-side) step t folds into step t+1's
  // repack (FOLD on even t); layer-0's flip is in the init; t=11's flip is
  // in the measurement algebra.
  #pragma clang loop unroll(disable)
  for (int i = 0; i < 4; ++i) {
    mm_step<false>(d, Bbuf + (2 * i + 3) * 2048 + lane * 4, hi, axor, maskA, maskB);
    mm_step<true >(d, Bbuf + (2 * i + 4) * 2048 + lane * 4, hi, axor, maskA, maskB);
  }
  mm_step<false>(d, Bbuf + 11 * 2048 + lane * 4, hi, axor, maskA, maskB);

  // ---- measurement (pending cond-flip folded into parity-split sums)
  float A0 = 0.f, A1 = 0.f, s00 = 0.f, s01 = 0.f;
  float zp0 = 0.f, zp1 = 0.f, zp3 = 0.f, zp4 = 0.f, zp5 = 0.f;
  #pragma unroll
  for (int mt = 0; mt < 2; ++mt)
    #pragma unroll
    for (int nt = 0; nt < 2; ++nt)
      #pragma unroll
      for (int r = 0; r < 16; ++r) {
        float v = d[mt][nt][r];
        float sq = v * v;
        const int par0 = (__builtin_popcount(r & 3) + __builtin_popcount(r >> 2) + mt) & 1;
        if (par0) A1 += sq; else A0 += sq;
        if (nt == 0) { if (par0) s01 += sq; else s00 += sq; }
        const int c0 = r & 1;
        const int c1 = (r ^ (r >> 1)) & 1;
        const int c3 = c1 ^ ((r >> 2) & 1);
        const int c4 = c3 ^ ((r >> 3) & 1);
        const int c5 = c4 ^ mt;
        zp0 += c0 ? -sq : sq;
        zp1 += c1 ? -sq : sq;
        zp3 += c3 ? -sq : sq;
        zp4 += c4 ? -sq : sq;
        zp5 += c5 ? -sq : sq;
      }
  const float sgnhi = hi ? -1.f : 1.f;
  const float tot   = A0 + A1;
  const float diff  = sgnhi * (A0 - A1);
  const float diffs = sgnhi * (2.f * (s00 - s01) - (A0 - A1));
  float z[12];
  z[0] = zp0;
  z[1] = zp1;
  z[2] = sgnhi * zp1;
  z[3] = sgnhi * zp3;
  z[4] = sgnhi * zp4;
  z[5] = sgnhi * zp5;
  #pragma unroll
  for (int j = 0; j < 5; ++j) {
    const int par = __builtin_popcount(lane & ((2 << j) - 1)) & 1;
    z[6 + j] = par ? -diff : diff;
  }
  {
    const int par = __builtin_popcount(lane & 31) & 1;
    z[11] = par ? -diffs : diffs;
  }
  const float tots = wave_sum(tot);
  #pragma unroll
  for (int w = 0; w < 12; ++w) z[w] = wave_sum(z[w]);

  if (lane == 0) {
    const float inv = 1.0f / tots;
    float o = post_b[0];
    #pragma unroll
    for (int w = 0; w < 12; ++w) o = fmaf(z[w] * inv, post_w[w], o);
    out[b] = o;
  }
}

extern "C" void kernel_launch(void* const* d_in, const int* in_sizes, int n_in,
                              void* d_out, int out_size, void* d_ws, size_t ws_size,
                              hipStream_t stream) {
  (void)in_sizes; (void)n_in; (void)out_size; (void)ws_size;
  const float* x       = (const float*)d_in[0];
  const float* pre_w   = (const float*)d_in[1];
  const float* pre_b   = (const float*)d_in[2];
  const float* weights = (const float*)d_in[3];
  const float* post_w  = (const float*)d_in[4];
  const float* post_b  = (const float*)d_in[5];
  float* out = (float*)d_out;
  u32* Bbuf = (u32*)d_ws;   // 12 * 2048 dwords = 96 KiB

  setup_mats<<<96, 256, 0, stream>>>(weights, Bbuf);
  dqc_main<<<BATCHN / 4, 256, 0, stream>>>(x, pre_w, pre_b, weights,
                                           post_w, post_b, Bbuf, out);
}

// Round 12
// 116.608 us; speedup vs baseline: 1.1231x; 1.1231x over previous
//
#include <hip/hip_runtime.h>
#include <math.h>

#define NQ 12
#define NL 6
#define BATCHN 8192
#define DIN 512

typedef _Float16 f16;
typedef __attribute__((ext_vector_type(8)))  _Float16 f16x8;
typedef __attribute__((ext_vector_type(16))) float    f32x16;
typedef unsigned int u32;
typedef __attribute__((ext_vector_type(4))) u32 u32x4;
typedef __attribute__((ext_vector_type(2))) int i32x2;

// ============================================================================
// 10-matmul formulation (R10) + R11 prologue/epilogue algebra.
// State = 64x64 (P: wires 0-5, Q: wires 6-11). MFMA contracts the
// reg-resident factor and swaps residency; CNOT chain sigma(d)=d^(d<<1) =
// sigmaP (x) sigmaQ (x) condflip(wire5->wire6); sigmaP/Q folded into next
// matrices (F6 = prefix-xor), cond-flip folded into the next repack
// (1 dpp + 1 bfi per word) or the measurement sign algebra.
// R10: layer 0 on the product state = per-qubit 2-vector rotation -> MM0+MM1
//   eliminated; its cond-flip = wire-6-swapped q-product per parity class.
// R11: (a) v0=(c-s)/sqrt2 = cos(h+pi/4), v1 = sin(h+pi/4); layer-0 rotation
//   adds to the angle -> u0/u1 = cos/sin(pre/8 + 1/8 + w0/(4pi) revolutions)
//   via v_cos/v_sin (kills 24 sincosf). (b) post_w folded into measurement
//   (wave_sum linearity): 13 wave_sums -> 2. (c) K-loop fully unrolled so
//   B-loads pipeline across steps.
//   MFMA 32x32x16 f16 layouts:
//   A[m][k]: m=lane&31, k=8*(lane>>5)+i ; B[k][n]: n=lane&31, k=8*(lane>>5)+i
//   D[m][n]: n=lane&31, m=(reg&3)+8*(reg>>2)+4*(lane>>5), tiles d[mt][nt].
// R5: accumulate directly into d (no temp) or scratch-spill.
// R8/R9: permlane32_swap repack; fold parity class indexes the OLD m-tile (s).
// ============================================================================

__device__ __forceinline__ u32 pkrtz(float a, float b) {
  auto p = __builtin_amdgcn_cvt_pkrtz(a, b);   // __fp16 ext_vector(2)
  return __builtin_bit_cast(u32, p);
}
__device__ __forceinline__ u32 bperm(int addr, u32 v) {
  return (u32)__builtin_amdgcn_ds_bpermute(addr, (int)v);
}
__device__ __forceinline__ float dppx1(float v) {  // lane xor 1 (quad_perm)
  return __int_as_float(__builtin_amdgcn_mov_dpp(__float_as_int(v), 0xB1, 0xF, 0xF, true));
}
__device__ __forceinline__ u32 dppx1u(u32 v) {
  return (u32)__builtin_amdgcn_mov_dpp((int)v, 0xB1, 0xF, 0xF, true);
}
__device__ __forceinline__ float dppx2(float v) {
  return __int_as_float(__builtin_amdgcn_mov_dpp(__float_as_int(v), 0x4E, 0xF, 0xF, true));
}
__device__ __forceinline__ float dppx8(float v) {  // row_ror:8 == xor 8
  return __int_as_float(__builtin_amdgcn_mov_dpp(__float_as_int(v), 0x128, 0xF, 0xF, true));
}
template <int PAT>
__device__ __forceinline__ float swzf(float v) {
  return __int_as_float(__builtin_amdgcn_ds_swizzle(__float_as_int(v), PAT));
}
__device__ __forceinline__ float wave_sum(float v) {
  v += dppx1(v);
  v += dppx2(v);
  v += swzf<0x101F>(v);   // xor 4
  v += dppx8(v);
  v += swzf<0x401F>(v);   // xor 16
  v += __shfl_xor(v, 32, 64);
  return v;
}
__device__ __forceinline__ f16x8 asf(const u32 a[4]) {
  u32x4 v; v.x = a[0]; v.y = a[1]; v.z = a[2]; v.w = a[3];
  return __builtin_bit_cast(f16x8, v);
}
__device__ __forceinline__ f16x8 ldB(const u32* __restrict__ p, int off) {
  u32x4 v = *(const u32x4*)(p + off);
  return __builtin_bit_cast(f16x8, v);
}

// fast sin/cos in revolutions (v_sin_f32/v_cos_f32 after fract reduction)
__device__ __forceinline__ void sincos_rev(float rev, float* s, float* c) {
  float r = rev - floorf(rev);
#if __has_builtin(__builtin_amdgcn_sinf) && __has_builtin(__builtin_amdgcn_cosf)
  *s = __builtin_amdgcn_sinf(r);
  *c = __builtin_amdgcn_cosf(r);
#else
  const float TWO_PI = 6.28318530717958647693f;
  sincosf(r * TWO_PI, s, c);
#endif
}

// half-swap across the lane-32 boundary: returns the two A-frag words.
#if __has_builtin(__builtin_amdgcn_permlane32_swap)
__device__ __forceinline__ void pswap(u32& a, u32& b) {
  i32x2 r = __builtin_amdgcn_permlane32_swap((int)a, (int)b, false, false);
  a = (u32)r.x; b = (u32)r.y;
}
#else
#define PSWAP_FALLBACK 1
__device__ __forceinline__ void pswap_fb(u32& a, u32& b, bool hi, int axor) {
  u32 xa = bperm(axor, a), xb = bperm(axor, b);
  u32 na = hi ? xb : a;
  u32 nb = hi ? b : xa;
  a = na; b = nb;
}
#endif

// conditional lane-xor-1 on a packed word (bfi idiom; halves have opposite
// flip conditions).
__device__ __forceinline__ u32 foldw(u32 w, u32 m) {
  u32 partner = dppx1u(w);
  return (m & partner) | (~m & w);
}

// ---------- setup: matrices (fp16, B-fragment order) from weights -----------
__global__ void setup_mats(const float* __restrict__ weights, u32* __restrict__ Bbuf) {
  const int mm = blockIdx.x >> 3;   // 0..11 ; layer = mm>>1, side: 0=P,1=Q
  const int l  = mm >> 1;
  const int qs = mm & 1;
  __shared__ float c6[6], s6[6];
  if (threadIdx.x < 6) {
    float h = 0.5f * weights[l * NQ + qs * 6 + threadIdx.x];
    c6[threadIdx.x] = cosf(h);
    s6[threadIdx.x] = sinf(h);
  }
  __syncthreads();
  const int t = (blockIdx.x & 7) * 256 + threadIdx.x;   // 0..2047
  const int lane = (t >> 2) & 63;
  const int fk   = t >> 8;          // nt*4 + kt
  const int kt   = fk & 3;
  const int nt   = fk >> 2;
  const int n     = nt * 32 + (lane & 31);
  const int kbase = kt * 16 + (lane >> 5) * 8 + (t & 3) * 2;
  float v[2];
  #pragma unroll
  for (int u = 0; u < 2; ++u) {
    int k = kbase + u;
    int bb = k;
    if (l >= 1) { bb ^= bb << 1; bb ^= bb << 2; bb ^= bb << 4; bb &= 63; } // F6 = prefix-xor
    float prod = 1.f;
    #pragma unroll
    for (int w = 0; w < 6; ++w) {
      const int aw = (n >> w) & 1, bw = (bb >> w) & 1;
      prod *= (aw == bw) ? c6[w] : (aw ? s6[w] : -s6[w]);  // RY: [[c,-s],[s,c]]
    }
    v[u] = prod;
  }
  Bbuf[mm * 2048 + t] = pkrtz(v[0], v[1]);
}

// ---------- one matmul step: repack prev D -> A frags, 16 MFMA --------------
template <bool FOLD>
__device__ __forceinline__ void mm_step(f32x16 (&d)[2][2], const u32* __restrict__ Bl,
                                        bool hi, int axor, u32 maskA, u32 maskB) {
  u32 fr[2][4][4];
  #pragma unroll
  for (int kt = 0; kt < 4; ++kt) {
    const int s  = kt >> 1;
    const int b0 = 4 * ((2 * kt) & 3);
    const int b1 = 4 * ((2 * kt + 1) & 3);
    #pragma unroll
    for (int mt = 0; mt < 2; ++mt) {
      u32 p0a = pkrtz(d[s][mt][b0 + 0], d[s][mt][b0 + 1]);
      u32 p0b = pkrtz(d[s][mt][b0 + 2], d[s][mt][b0 + 3]);
      u32 p1a = pkrtz(d[s][mt][b1 + 0], d[s][mt][b1 + 1]);
      u32 p1b = pkrtz(d[s][mt][b1 + 2], d[s][mt][b1 + 3]);
      if (FOLD) {
        const int PAR4[4] = {0, 1, 1, 0};
        const int ka = (PAR4[b0 >> 2] + s) & 1;   // low-half class of p0a
        const int kc = (PAR4[b1 >> 2] + s) & 1;   // low-half class of p1a
        p0a = foldw(p0a, ka ? maskB : maskA);
        p0b = foldw(p0b, ka ? maskA : maskB);
        p1a = foldw(p1a, kc ? maskB : maskA);
        p1b = foldw(p1b, kc ? maskA : maskB);
      }
#ifdef PSWAP_FALLBACK
      pswap_fb(p0a, p1a, hi, axor);
      pswap_fb(p0b, p1b, hi, axor);
#else
      pswap(p0a, p1a);
      pswap(p0b, p1b);
#endif
      fr[mt][kt][0] = p0a;
      fr[mt][kt][1] = p0b;
      fr[mt][kt][2] = p1a;
      fr[mt][kt][3] = p1b;
    }
  }
  #pragma unroll
  for (int kt = 0; kt < 4; ++kt) {
    f16x8 A0 = asf(fr[0][kt]);
    f16x8 A1 = asf(fr[1][kt]);
    f16x8 B0 = ldB(Bl, (0 * 4 + kt) * 256);
    f16x8 B1 = ldB(Bl, (1 * 4 + kt) * 256);
    if (kt == 0) {
      f32x16 z{};
      d[0][0] = __builtin_amdgcn_mfma_f32_32x32x16_f16(A0, B0, z, 0, 0, 0);
      d[0][1] = __builtin_amdgcn_mfma_f32_32x32x16_f16(A0, B1, z, 0, 0, 0);
      d[1][0] = __builtin_amdgcn_mfma_f32_32x32x16_f16(A1, B0, z, 0, 0, 0);
      d[1][1] = __builtin_amdgcn_mfma_f32_32x32x16_f16(A1, B1, z, 0, 0, 0);
    } else {
      d[0][0] = __builtin_amdgcn_mfma_f32_32x32x16_f16(A0, B0, d[0][0], 0, 0, 0);
      d[0][1] = __builtin_amdgcn_mfma_f32_32x32x16_f16(A0, B1, d[0][1], 0, 0, 0);
      d[1][0] = __builtin_amdgcn_mfma_f32_32x32x16_f16(A1, B0, d[1][0], 0, 0, 0);
      d[1][1] = __builtin_amdgcn_mfma_f32_32x32x16_f16(A1, B1, d[1][1], 0, 0, 0);
    }
  }
}

__global__ void __launch_bounds__(256) __attribute__((amdgpu_waves_per_eu(4)))
dqc_main(const float* __restrict__ x,
         const float* __restrict__ pre_w,
         const float* __restrict__ pre_b,
         const float* __restrict__ weights,
         const float* __restrict__ post_w,
         const float* __restrict__ post_b,
         const u32* __restrict__ Bbuf,
         float* __restrict__ out)
{
  const int lane = threadIdx.x & 63;
  const bool hi  = lane >= 32;
  const int b    = blockIdx.x * 4 + (threadIdx.x >> 6);
  const int axor = (lane ^ 32) << 2;
  // flip-partner masks: class k flips lower f16 when k ^ hi == 1.
  const u32 maskA = hi ? 0x0000FFFFu : 0xFFFF0000u;   // parity-class 0
  const u32 maskB = ~maskA;                            // parity-class 1

  // ---- pre-GEMM: pre[w] = x[b,:] . pre_w[w,:]
  float acc[NQ];
  const float* xr = x + (size_t)b * DIN + lane * 8;
  const float4 xa = *(const float4*)(xr);
  const float4 xb = *(const float4*)(xr + 4);
  #pragma unroll
  for (int w = 0; w < NQ; ++w) {
    const float* wr = pre_w + w * DIN + lane * 8;
    const float4 wa = *(const float4*)(wr);
    const float4 wb = *(const float4*)(wr + 4);
    acc[w] = xa.x * wa.x + xa.y * wa.y + xa.z * wa.z + xa.w * wa.w
           + xb.x * wb.x + xb.y * wb.y + xb.z * wb.z + xb.w * wb.w;
  }
  #pragma unroll
  for (int w = 0; w < NQ; ++w) acc[w] = wave_sum(acc[w]);

  // ---- R11: u0 = cos(theta), u1 = sin(theta),
  // theta = (acc+pre_b)*pi/4 + pi/4 + 0.5*weights[0][w]  (layer-0 folded).
  // In revolutions: rev = acc/8 + (0.125 + pre_b/8 + weights[0][w]/(4pi)).
  const float INV_4PI = 0.07957747154594766788f;
  float u0[NQ], u1[NQ];
  #pragma unroll
  for (int w = 0; w < NQ; ++w) {
    const float cw2 = 0.125f + pre_b[w] * 0.125f + weights[w] * INV_4PI;
    const float rev = fmaf(acc[w], 0.125f, cw2);
    sincos_rev(rev, &u1[w], &u0[w]);
  }

  // ---- build MM2's A-frags directly, with layer-0's cond-flip applied:
  // element(m=q, k=p) = P(p) * Q(q ^ (par(p) & 1 on wire6)).
  // p = 16*kt + 8*hi + j: par(p) = PKT[kt] ^ hi ^ parity(j).
  float base8[8];   // wires 0-2 (j bits)
  #pragma unroll
  for (int j = 0; j < 8; ++j)
    base8[j] = ((j & 1) ? u1[0] : u0[0]) * ((j & 2) ? u1[1] : u0[1]) * ((j & 4) ? u1[2] : u0[2]);
  float hiP[4];     // wires 3(hi),4,5(kt bits)
  #pragma unroll
  for (int kt = 0; kt < 4; ++kt)
    hiP[kt] = (hi ? u1[3] : u0[3]) * ((kt & 1) ? u1[4] : u0[4]) * ((kt & 2) ? u1[5] : u0[5]);
  const float q5 = ((lane & 2) ? u1[7] : u0[7]) * ((lane & 4) ? u1[8] : u0[8])
                 * ((lane & 8) ? u1[9] : u0[9]) * ((lane & 16) ? u1[10] : u0[10]);
  const float qA = q5 * ((lane & 1) ? u1[6] : u0[6]);   // Q(q)
  const float qB = q5 * ((lane & 1) ? u0[6] : u1[6]);   // Q(q ^ wire6)
  const float qeven = hi ? qB : qA;   // class par(p)=0 (hi folded in)
  const float qodd  = hi ? qA : qB;   // class par(p)=1
  const float qe0 = qeven * u0[11], qo0 = qodd * u0[11];   // mt = 0 (wire11=0)
  const float qe1 = qeven * u1[11], qo1 = qodd * u1[11];   // mt = 1

  f32x16 d[2][2];
  {
    const u32* Bl = Bbuf + 2 * 2048 + lane * 4;   // matmul index 2 (layer-1 P, F6)
    const int PKT[4] = {0, 1, 1, 0};   // parity(kt)
    const int PDW[4] = {0, 1, 1, 0};   // parity(j=2*dw)
    #pragma unroll
    for (int kt = 0; kt < 4; ++kt) {
      u32 a0[4], a1[4];
      #pragma unroll
      for (int dw = 0; dw < 4; ++dw) {
        const float e0 = base8[2 * dw] * hiP[kt];
        const float e1 = base8[2 * dw + 1] * hiP[kt];
        const bool cls = (PKT[kt] ^ PDW[dw]) != 0;   // class of e0 (e1 is ^1)
        a0[dw] = pkrtz((cls ? qo0 : qe0) * e0, (cls ? qe0 : qo0) * e1);
        a1[dw] = pkrtz((cls ? qo1 : qe1) * e0, (cls ? qe1 : qo1) * e1);
      }
      f16x8 A0 = asf(a0), A1 = asf(a1);
      f16x8 B0 = ldB(Bl, (0 * 4 + kt) * 256);
      f16x8 B1 = ldB(Bl, (1 * 4 + kt) * 256);
      if (kt == 0) {
        f32x16 z{};
        d[0][0] = __builtin_amdgcn_mfma_f32_32x32x16_f16(A0, B0, z, 0, 0, 0);
        d[0][1] = __builtin_amdgcn_mfma_f32_32x32x16_f16(A0, B1, z, 0, 0, 0);
        d[1][0] = __builtin_amdgcn_mfma_f32_32x32x16_f16(A1, B0, z, 0, 0, 0);
        d[1][1] = __builtin_amdgcn_mfma_f32_32x32x16_f16(A1, B1, z, 0, 0, 0);
      } else {
        d[0][0] = __builtin_amdgcn_mfma_f32_32x32x16_f16(A0, B0, d[0][0], 0, 0, 0);
        d[0][1] = __builtin_amdgcn_mfma_f32_32x32x16_f16(A0, B1, d[0][1], 0, 0, 0);
        d[1][0] = __builtin_amdgcn_mfma_f32_32x32x16_f16(A1, B0, d[1][0], 0, 0, 0);
        d[1][1] = __builtin_amdgcn_mfma_f32_32x32x16_f16(A1, B1, d[1][1], 0, 0, 0);
      }
    }
  }

  // ---- MM 3..11 (fully unrolled so B-loads pipeline across steps).
  // Flip after odd (Q-side) step t folds into step t+1's repack (FOLD on
  // even t); layer-0's flip is in the init; t=11's flip is in the
  // measurement algebra.
  #pragma unroll
  for (int i = 0; i < 4; ++i) {
    mm_step<false>(d, Bbuf + (2 * i + 3) * 2048 + lane * 4, hi, axor, maskA, maskB);
    mm_step<true >(d, Bbuf + (2 * i + 4) * 2048 + lane * 4, hi, axor, maskA, maskB);
  }
  mm_step<false>(d, Bbuf + 11 * 2048 + lane * 4, hi, axor, maskA, maskB);

  // ---- measurement with post_w folded in (wave_sum linearity):
  // per-element coefficients are wave-uniform (compile-time signs x post_w).
  const float pw0 = post_w[0], pw1 = post_w[1], pw2 = post_w[2],
              pw3 = post_w[3], pw4 = post_w[4], pw5 = post_w[5];
  float A0s = 0.f, A1s = 0.f, s00 = 0.f, s01 = 0.f, accA = 0.f, accB = 0.f;
  #pragma unroll
  for (int mt = 0; mt < 2; ++mt)
    #pragma unroll
    for (int nt = 0; nt < 2; ++nt)
      #pragma unroll
      for (int r = 0; r < 16; ++r) {
        float v = d[mt][nt][r];
        float sq = v * v;
        const int par0 = (__builtin_popcount(r & 3) + __builtin_popcount(r >> 2) + mt) & 1;
        if (par0) A1s += sq; else A0s += sq;
        if (nt == 0) { if (par0) s01 += sq; else s00 += sq; }
        const int c0 = r & 1;
        const int c1 = (r ^ (r >> 1)) & 1;
        const int c3 = c1 ^ ((r >> 2) & 1);
        const int c4 = c3 ^ ((r >> 3) & 1);
        const int c5 = c4 ^ mt;
        const float ca = (c0 ? -pw0 : pw0) + (c1 ? -pw1 : pw1);
        const float cb = (c1 ? -pw2 : pw2) + (c3 ? -pw3 : pw3)
                       + (c4 ? -pw4 : pw4) + (c5 ? -pw5 : pw5);
        accA = fmaf(ca, sq, accA);
        accB = fmaf(cb, sq, accB);
      }
  const float sgnhi = hi ? -1.f : 1.f;
  const float tot   = A0s + A1s;
  const float diff  = sgnhi * (A0s - A1s);
  const float diffs = sgnhi * (2.f * (s00 - s01) - (A0s - A1s));
  // q'-side lane signs
  float Sq = 0.f;
  #pragma unroll
  for (int j = 0; j < 5; ++j) {
    const int par = __builtin_popcount(lane & ((2 << j) - 1)) & 1;
    Sq += par ? -post_w[6 + j] : post_w[6 + j];
  }
  const float s5 = (__builtin_popcount(lane & 31) & 1) ? -post_w[11] : post_w[11];
  const float zcomb = accA + sgnhi * accB + diff * Sq + diffs * s5;

  const float tots = wave_sum(tot);
  const float zs   = wave_sum(zcomb);

  if (lane == 0) {
    out[b] = fmaf(zs, 1.0f / tots, post_b[0]);
  }
}

extern "C" void kernel_launch(void* const* d_in, const int* in_sizes, int n_in,
                              void* d_out, int out_size, void* d_ws, size_t ws_size,
                              hipStream_t stream) {
  (void)in_sizes; (void)n_in; (void)out_size; (void)ws_size;
  const float* x       = (const float*)d_in[0];
  const float* pre_w   = (const float*)d_in[1];
  const float* pre_b   = (const float*)d_in[2];
  const float* weights = (const float*)d_in[3];
  const float* post_w  = (const float*)d_in[4];
  const float* post_b  = (const float*)d_in[5];
  float* out = (float*)d_out;
  u32* Bbuf = (u32*)d_ws;   // 12 * 2048 dwords = 96 KiB

  setup_mats<<<96, 256, 0, stream>>>(weights, Bbuf);
  dqc_main<<<BATCHN / 4, 256, 0, stream>>>(x, pre_w, pre_b, weights,
                                           post_w, post_b, Bbuf, out);
}

// Round 13
// 115.446 us; speedup vs baseline: 1.1345x; 1.0101x over previous
//
#include <hip/hip_runtime.h>
#include <math.h>

#define NQ 12
#define NL 6
#define BATCHN 8192
#define DIN 512

typedef _Float16 f16;
typedef __attribute__((ext_vector_type(8)))  _Float16 f16x8;
typedef __attribute__((ext_vector_type(16))) float    f32x16;
typedef unsigned int u32;
typedef __attribute__((ext_vector_type(4))) u32 u32x4;
typedef __attribute__((ext_vector_type(2))) int i32x2;

// ============================================================================
// 10-matmul formulation. State = 64x64 (P: wires 0-5, Q: wires 6-11). MFMA
// contracts the reg-resident factor and swaps residency; CNOT chain
// sigma(d)=d^(d<<1) = sigmaP (x) sigmaQ (x) condflip(wire5->wire6); sigmaP/Q
// folded into next matrices (F6 = prefix-xor), cond-flip folded into the next
// repack (1 dpp + 1 bfi per word) or the measurement sign algebra.
// R10: layer 0 on the product state -> MM0+MM1 eliminated (init builds MM2's
//   A-frags with layer-0's rotation and cond-flip applied exactly).
// R11: trig identity (u0/u1 = cos/sin of one angle, v_cos/v_sin); post_w
//   folded into measurement (13 wave_sums -> 2); K-loop fully unrolled.
// R12: waves_per_eu(4)'s hard 128-reg budget caused a 2.4 MB scratch spill
//   (R11 counters) -> relax to (3,4); B-loads issued before repack VALU.
//   MFMA floor at this blocking: 8 waves/SIMD x 160 MFMA x ~32 cyc = 17 us.
// R5: accumulate directly into d (no temp) or scratch-spill.
// R8/R9: permlane32_swap repack; fold parity class indexes the OLD m-tile (s).
// ============================================================================

__device__ __forceinline__ u32 pkrtz(float a, float b) {
  auto p = __builtin_amdgcn_cvt_pkrtz(a, b);   // __fp16 ext_vector(2)
  return __builtin_bit_cast(u32, p);
}
__device__ __forceinline__ u32 bperm(int addr, u32 v) {
  return (u32)__builtin_amdgcn_ds_bpermute(addr, (int)v);
}
__device__ __forceinline__ float dppx1(float v) {  // lane xor 1 (quad_perm)
  return __int_as_float(__builtin_amdgcn_mov_dpp(__float_as_int(v), 0xB1, 0xF, 0xF, true));
}
__device__ __forceinline__ u32 dppx1u(u32 v) {
  return (u32)__builtin_amdgcn_mov_dpp((int)v, 0xB1, 0xF, 0xF, true);
}
__device__ __forceinline__ float dppx2(float v) {
  return __int_as_float(__builtin_amdgcn_mov_dpp(__float_as_int(v), 0x4E, 0xF, 0xF, true));
}
__device__ __forceinline__ float dppx8(float v) {  // row_ror:8 == xor 8
  return __int_as_float(__builtin_amdgcn_mov_dpp(__float_as_int(v), 0x128, 0xF, 0xF, true));
}
template <int PAT>
__device__ __forceinline__ float swzf(float v) {
  return __int_as_float(__builtin_amdgcn_ds_swizzle(__float_as_int(v), PAT));
}
__device__ __forceinline__ float wave_sum(float v) {
  v += dppx1(v);
  v += dppx2(v);
  v += swzf<0x101F>(v);   // xor 4
  v += dppx8(v);
  v += swzf<0x401F>(v);   // xor 16
  v += __shfl_xor(v, 32, 64);
  return v;
}
__device__ __forceinline__ f16x8 asf(const u32 a[4]) {
  u32x4 v; v.x = a[0]; v.y = a[1]; v.z = a[2]; v.w = a[3];
  return __builtin_bit_cast(f16x8, v);
}
__device__ __forceinline__ f16x8 ldB(const u32* __restrict__ p, int off) {
  u32x4 v = *(const u32x4*)(p + off);
  return __builtin_bit_cast(f16x8, v);
}

// fast sin/cos in revolutions (v_sin_f32/v_cos_f32 after fract reduction)
__device__ __forceinline__ void sincos_rev(float rev, float* s, float* c) {
  float r = rev - floorf(rev);
#if __has_builtin(__builtin_amdgcn_sinf) && __has_builtin(__builtin_amdgcn_cosf)
  *s = __builtin_amdgcn_sinf(r);
  *c = __builtin_amdgcn_cosf(r);
#else
  const float TWO_PI = 6.28318530717958647693f;
  sincosf(r * TWO_PI, s, c);
#endif
}

// half-swap across the lane-32 boundary: returns the two A-frag words.
#if __has_builtin(__builtin_amdgcn_permlane32_swap)
__device__ __forceinline__ void pswap(u32& a, u32& b) {
  i32x2 r = __builtin_amdgcn_permlane32_swap((int)a, (int)b, false, false);
  a = (u32)r.x; b = (u32)r.y;
}
#else
#define PSWAP_FALLBACK 1
__device__ __forceinline__ void pswap_fb(u32& a, u32& b, bool hi, int axor) {
  u32 xa = bperm(axor, a), xb = bperm(axor, b);
  u32 na = hi ? xb : a;
  u32 nb = hi ? b : xa;
  a = na; b = nb;
}
#endif

// conditional lane-xor-1 on a packed word (bfi idiom; halves have opposite
// flip conditions).
__device__ __forceinline__ u32 foldw(u32 w, u32 m) {
  u32 partner = dppx1u(w);
  return (m & partner) | (~m & w);
}

// ---------- setup: matrices (fp16, B-fragment order) from weights -----------
__global__ void setup_mats(const float* __restrict__ weights, u32* __restrict__ Bbuf) {
  const int mm = blockIdx.x >> 3;   // 0..11 ; layer = mm>>1, side: 0=P,1=Q
  const int l  = mm >> 1;
  const int qs = mm & 1;
  __shared__ float c6[6], s6[6];
  if (threadIdx.x < 6) {
    float h = 0.5f * weights[l * NQ + qs * 6 + threadIdx.x];
    c6[threadIdx.x] = cosf(h);
    s6[threadIdx.x] = sinf(h);
  }
  __syncthreads();
  const int t = (blockIdx.x & 7) * 256 + threadIdx.x;   // 0..2047
  const int lane = (t >> 2) & 63;
  const int fk   = t >> 8;          // nt*4 + kt
  const int kt   = fk & 3;
  const int nt   = fk >> 2;
  const int n     = nt * 32 + (lane & 31);
  const int kbase = kt * 16 + (lane >> 5) * 8 + (t & 3) * 2;
  float v[2];
  #pragma unroll
  for (int u = 0; u < 2; ++u) {
    int k = kbase + u;
    int bb = k;
    if (l >= 1) { bb ^= bb << 1; bb ^= bb << 2; bb ^= bb << 4; bb &= 63; } // F6 = prefix-xor
    float prod = 1.f;
    #pragma unroll
    for (int w = 0; w < 6; ++w) {
      const int aw = (n >> w) & 1, bw = (bb >> w) & 1;
      prod *= (aw == bw) ? c6[w] : (aw ? s6[w] : -s6[w]);  // RY: [[c,-s],[s,c]]
    }
    v[u] = prod;
  }
  Bbuf[mm * 2048 + t] = pkrtz(v[0], v[1]);
}

// ---------- one matmul step: repack prev D -> A frags, 16 MFMA --------------
// B-loads issued FIRST so their latency overlaps the ~40 repack VALU cycles.
template <bool FOLD>
__device__ __forceinline__ void mm_step(f32x16 (&d)[2][2], const u32* __restrict__ Bl,
                                        bool hi, int axor, u32 maskA, u32 maskB) {
  f16x8 B[2][4];
  #pragma unroll
  for (int kt = 0; kt < 4; ++kt) {
    B[0][kt] = ldB(Bl, (0 * 4 + kt) * 256);
    B[1][kt] = ldB(Bl, (1 * 4 + kt) * 256);
  }
  u32 fr[2][4][4];
  #pragma unroll
  for (int kt = 0; kt < 4; ++kt) {
    const int s  = kt >> 1;
    const int b0 = 4 * ((2 * kt) & 3);
    const int b1 = 4 * ((2 * kt + 1) & 3);
    #pragma unroll
    for (int mt = 0; mt < 2; ++mt) {
      u32 p0a = pkrtz(d[s][mt][b0 + 0], d[s][mt][b0 + 1]);
      u32 p0b = pkrtz(d[s][mt][b0 + 2], d[s][mt][b0 + 3]);
      u32 p1a = pkrtz(d[s][mt][b1 + 0], d[s][mt][b1 + 1]);
      u32 p1b = pkrtz(d[s][mt][b1 + 2], d[s][mt][b1 + 3]);
      if (FOLD) {
        const int PAR4[4] = {0, 1, 1, 0};
        const int ka = (PAR4[b0 >> 2] + s) & 1;   // low-half class of p0a
        const int kc = (PAR4[b1 >> 2] + s) & 1;   // low-half class of p1a
        p0a = foldw(p0a, ka ? maskB : maskA);
        p0b = foldw(p0b, ka ? maskA : maskB);
        p1a = foldw(p1a, kc ? maskB : maskA);
        p1b = foldw(p1b, kc ? maskA : maskB);
      }
#ifdef PSWAP_FALLBACK
      pswap_fb(p0a, p1a, hi, axor);
      pswap_fb(p0b, p1b, hi, axor);
#else
      pswap(p0a, p1a);
      pswap(p0b, p1b);
#endif
      fr[mt][kt][0] = p0a;
      fr[mt][kt][1] = p0b;
      fr[mt][kt][2] = p1a;
      fr[mt][kt][3] = p1b;
    }
  }
  #pragma unroll
  for (int kt = 0; kt < 4; ++kt) {
    f16x8 A0 = asf(fr[0][kt]);
    f16x8 A1 = asf(fr[1][kt]);
    if (kt == 0) {
      f32x16 z{};
      d[0][0] = __builtin_amdgcn_mfma_f32_32x32x16_f16(A0, B[0][kt], z, 0, 0, 0);
      d[0][1] = __builtin_amdgcn_mfma_f32_32x32x16_f16(A0, B[1][kt], z, 0, 0, 0);
      d[1][0] = __builtin_amdgcn_mfma_f32_32x32x16_f16(A1, B[0][kt], z, 0, 0, 0);
      d[1][1] = __builtin_amdgcn_mfma_f32_32x32x16_f16(A1, B[1][kt], z, 0, 0, 0);
    } else {
      d[0][0] = __builtin_amdgcn_mfma_f32_32x32x16_f16(A0, B[0][kt], d[0][0], 0, 0, 0);
      d[0][1] = __builtin_amdgcn_mfma_f32_32x32x16_f16(A0, B[1][kt], d[0][1], 0, 0, 0);
      d[1][0] = __builtin_amdgcn_mfma_f32_32x32x16_f16(A1, B[0][kt], d[1][0], 0, 0, 0);
      d[1][1] = __builtin_amdgcn_mfma_f32_32x32x16_f16(A1, B[1][kt], d[1][1], 0, 0, 0);
    }
  }
}

__global__ void __launch_bounds__(256) __attribute__((amdgpu_waves_per_eu(3, 4)))
dqc_main(const float* __restrict__ x,
         const float* __restrict__ pre_w,
         const float* __restrict__ pre_b,
         const float* __restrict__ weights,
         const float* __restrict__ post_w,
         const float* __restrict__ post_b,
         const u32* __restrict__ Bbuf,
         float* __restrict__ out)
{
  const int lane = threadIdx.x & 63;
  const bool hi  = lane >= 32;
  const int b    = blockIdx.x * 4 + (threadIdx.x >> 6);
  const int axor = (lane ^ 32) << 2;
  // flip-partner masks: class k flips lower f16 when k ^ hi == 1.
  const u32 maskA = hi ? 0x0000FFFFu : 0xFFFF0000u;   // parity-class 0
  const u32 maskB = ~maskA;                            // parity-class 1

  // ---- pre-GEMM: pre[w] = x[b,:] . pre_w[w,:]
  float acc[NQ];
  const float* xr = x + (size_t)b * DIN + lane * 8;
  const float4 xa = *(const float4*)(xr);
  const float4 xb = *(const float4*)(xr + 4);
  #pragma unroll
  for (int w = 0; w < NQ; ++w) {
    const float* wr = pre_w + w * DIN + lane * 8;
    const float4 wa = *(const float4*)(wr);
    const float4 wb = *(const float4*)(wr + 4);
    acc[w] = xa.x * wa.x + xa.y * wa.y + xa.z * wa.z + xa.w * wa.w
           + xb.x * wb.x + xb.y * wb.y + xb.z * wb.z + xb.w * wb.w;
  }
  #pragma unroll
  for (int w = 0; w < NQ; ++w) acc[w] = wave_sum(acc[w]);

  // ---- u0 = cos(theta), u1 = sin(theta),
  // theta = (acc+pre_b)*pi/4 + pi/4 + 0.5*weights[0][w]  (layer-0 folded).
  const float INV_4PI = 0.07957747154594766788f;
  float u0[NQ], u1[NQ];
  #pragma unroll
  for (int w = 0; w < NQ; ++w) {
    const float cw2 = 0.125f + pre_b[w] * 0.125f + weights[w] * INV_4PI;
    const float rev = fmaf(acc[w], 0.125f, cw2);
    sincos_rev(rev, &u1[w], &u0[w]);
  }

  // ---- build MM2's A-frags directly, with layer-0's cond-flip applied:
  // element(m=q, k=p) = P(p) * Q(q ^ (par(p) & 1 on wire6)).
  float base8[8];   // wires 0-2 (j bits)
  #pragma unroll
  for (int j = 0; j < 8; ++j)
    base8[j] = ((j & 1) ? u1[0] : u0[0]) * ((j & 2) ? u1[1] : u0[1]) * ((j & 4) ? u1[2] : u0[2]);
  float hiP[4];     // wires 3(hi),4,5(kt bits)
  #pragma unroll
  for (int kt = 0; kt < 4; ++kt)
    hiP[kt] = (hi ? u1[3] : u0[3]) * ((kt & 1) ? u1[4] : u0[4]) * ((kt & 2) ? u1[5] : u0[5]);
  const float q5 = ((lane & 2) ? u1[7] : u0[7]) * ((lane & 4) ? u1[8] : u0[8])
                 * ((lane & 8) ? u1[9] : u0[9]) * ((lane & 16) ? u1[10] : u0[10]);
  const float qA = q5 * ((lane & 1) ? u1[6] : u0[6]);   // Q(q)
  const float qB = q5 * ((lane & 1) ? u0[6] : u1[6]);   // Q(q ^ wire6)
  const float qeven = hi ? qB : qA;   // class par(p)=0 (hi folded in)
  const float qodd  = hi ? qA : qB;   // class par(p)=1
  const float qe0 = qeven * u0[11], qo0 = qodd * u0[11];   // mt = 0
  const float qe1 = qeven * u1[11], qo1 = qodd * u1[11];   // mt = 1

  f32x16 d[2][2];
  {
    const u32* Bl = Bbuf + 2 * 2048 + lane * 4;   // matmul index 2 (layer-1 P, F6)
    const int PKT[4] = {0, 1, 1, 0};   // parity(kt)
    const int PDW[4] = {0, 1, 1, 0};   // parity(j=2*dw)
    #pragma unroll
    for (int kt = 0; kt < 4; ++kt) {
      u32 a0[4], a1[4];
      #pragma unroll
      for (int dw = 0; dw < 4; ++dw) {
        const float e0 = base8[2 * dw] * hiP[kt];
        const float e1 = base8[2 * dw + 1] * hiP[kt];
        const bool cls = (PKT[kt] ^ PDW[dw]) != 0;   // class of e0 (e1 is ^1)
        a0[dw] = pkrtz((cls ? qo0 : qe0) * e0, (cls ? qe0 : qo0) * e1);
        a1[dw] = pkrtz((cls ? qo1 : qe1) * e0, (cls ? qe1 : qo1) * e1);
      }
      f16x8 A0 = asf(a0), A1 = asf(a1);
      f16x8 B0 = ldB(Bl, (0 * 4 + kt) * 256);
      f16x8 B1 = ldB(Bl, (1 * 4 + kt) * 256);
      if (kt == 0) {
        f32x16 z{};
        d[0][0] = __builtin_amdgcn_mfma_f32_32x32x16_f16(A0, B0, z, 0, 0, 0);
        d[0][1] = __builtin_amdgcn_mfma_f32_32x32x16_f16(A0, B1, z, 0, 0, 0);
        d[1][0] = __builtin_amdgcn_mfma_f32_32x32x16_f16(A1, B0, z, 0, 0, 0);
        d[1][1] = __builtin_amdgcn_mfma_f32_32x32x16_f16(A1, B1, z, 0, 0, 0);
      } else {
        d[0][0] = __builtin_amdgcn_mfma_f32_32x32x16_f16(A0, B0, d[0][0], 0, 0, 0);
        d[0][1] = __builtin_amdgcn_mfma_f32_32x32x16_f16(A0, B1, d[0][1], 0, 0, 0);
        d[1][0] = __builtin_amdgcn_mfma_f32_32x32x16_f16(A1, B0, d[1][0], 0, 0, 0);
        d[1][1] = __builtin_amdgcn_mfma_f32_32x32x16_f16(A1, B1, d[1][1], 0, 0, 0);
      }
    }
  }

  // ---- MM 3..11 (fully unrolled). Flip after odd (Q-side) step t folds into
  // step t+1's repack (FOLD on even t); layer-0's flip is in the init;
  // t=11's flip is in the measurement algebra.
  #pragma unroll
  for (int i = 0; i < 4; ++i) {
    mm_step<false>(d, Bbuf + (2 * i + 3) * 2048 + lane * 4, hi, axor, maskA, maskB);
    mm_step<true >(d, Bbuf + (2 * i + 4) * 2048 + lane * 4, hi, axor, maskA, maskB);
  }
  mm_step<false>(d, Bbuf + 11 * 2048 + lane * 4, hi, axor, maskA, maskB);

  // ---- measurement with post_w folded in (wave_sum linearity).
  const float pw0 = post_w[0], pw1 = post_w[1], pw2 = post_w[2],
              pw3 = post_w[3], pw4 = post_w[4], pw5 = post_w[5];
  float A0s = 0.f, A1s = 0.f, s00 = 0.f, s01 = 0.f, accA = 0.f, accB = 0.f;
  #pragma unroll
  for (int mt = 0; mt < 2; ++mt)
    #pragma unroll
    for (int nt = 0; nt < 2; ++nt)
      #pragma unroll
      for (int r = 0; r < 16; ++r) {
        float v = d[mt][nt][r];
        float sq = v * v;
        const int par0 = (__builtin_popcount(r & 3) + __builtin_popcount(r >> 2) + mt) & 1;
        if (par0) A1s += sq; else A0s += sq;
        if (nt == 0) { if (par0) s01 += sq; else s00 += sq; }
        const int c0 = r & 1;
        const int c1 = (r ^ (r >> 1)) & 1;
        const int c3 = c1 ^ ((r >> 2) & 1);
        const int c4 = c3 ^ ((r >> 3) & 1);
        const int c5 = c4 ^ mt;
        const float ca = (c0 ? -pw0 : pw0) + (c1 ? -pw1 : pw1);
        const float cb = (c1 ? -pw2 : pw2) + (c3 ? -pw3 : pw3)
                       + (c4 ? -pw4 : pw4) + (c5 ? -pw5 : pw5);
        accA = fmaf(ca, sq, accA);
        accB = fmaf(cb, sq, accB);
      }
  const float sgnhi = hi ? -1.f : 1.f;
  const float tot   = A0s + A1s;
  const float diff  = sgnhi * (A0s - A1s);
  const float diffs = sgnhi * (2.f * (s00 - s01) - (A0s - A1s));
  float Sq = 0.f;
  #pragma unroll
  for (int j = 0; j < 5; ++j) {
    const int par = __builtin_popcount(lane & ((2 << j) - 1)) & 1;
    Sq += par ? -post_w[6 + j] : post_w[6 + j];
  }
  const float s5 = (__builtin_popcount(lane & 31) & 1) ? -post_w[11] : post_w[11];
  const float zcomb = accA + sgnhi * accB + diff * Sq + diffs * s5;

  const float tots = wave_sum(tot);
  const float zs   = wave_sum(zcomb);

  if (lane == 0) {
    out[b] = fmaf(zs, 1.0f / tots, post_b[0]);
  }
}

extern "C" void kernel_launch(void* const* d_in, const int* in_sizes, int n_in,
                              void* d_out, int out_size, void* d_ws, size_t ws_size,
                              hipStream_t stream) {
  (void)in_sizes; (void)n_in; (void)out_size; (void)ws_size;
  const float* x       = (const float*)d_in[0];
  const float* pre_w   = (const float*)d_in[1];
  const float* pre_b   = (const float*)d_in[2];
  const float* weights = (const float*)d_in[3];
  const float* post_w  = (const float*)d_in[4];
  const float* post_b  = (const float*)d_in[5];
  float* out = (float*)d_out;
  u32* Bbuf = (u32*)d_ws;   // 12 * 2048 dwords = 96 KiB

  setup_mats<<<96, 256, 0, stream>>>(weights, Bbuf);
  dqc_main<<<BATCHN / 4, 256, 0, stream>>>(x, pre_w, pre_b, weights,
                                           post_w, post_b, Bbuf, out);
}